// Round 1
// baseline (1762.062 us; speedup 1.0000x reference)
//
#include <hip/hip_runtime.h>
#include <math.h>

// Problem dims
#define B_  2
#define S_  1024
#define H_  768
#define NH_ 12
#define DH_ 64
#define FF_ 3072
#define L_  4

typedef short v8s __attribute__((ext_vector_type(8)));
typedef float v4f __attribute__((ext_vector_type(4)));

static __device__ __forceinline__ unsigned short f2bf(float f) {
    unsigned int u = __float_as_uint(f);
    unsigned int r = (u + 0x7fffu + ((u >> 16) & 1u)) >> 16;
    return (unsigned short)r;
}

// ---------------- fp32 -> bf16 convert (no transpose) ----------------
__global__ void conv_bf16_k(const float* __restrict__ in, unsigned short* __restrict__ out, int n) {
    int i = blockIdx.x * 256 + threadIdx.x;
    if (i < n) out[i] = f2bf(in[i]);
}

// ---------------- fp32 [K,N] -> bf16 [N,K] transpose-convert ----------------
__global__ __launch_bounds__(256) void transpose_convert(
    const float* __restrict__ W, unsigned short* __restrict__ Wt,
    int K, int N, size_t in_lstride, size_t out_lstride)
{
    __shared__ float tile[32][33];
    const int l = blockIdx.z;
    const float* src = W + (size_t)l * in_lstride;
    unsigned short* dst = Wt + (size_t)l * out_lstride;
    const int k0 = blockIdx.x * 32;
    const int n0 = blockIdx.y * 32;
    const int t = threadIdx.x;
    const int tc = t & 31, tr = t >> 5;
#pragma unroll
    for (int i = 0; i < 4; ++i) {
        int r = tr + i * 8;
        tile[r][tc] = src[(size_t)(k0 + r) * N + n0 + tc];
    }
    __syncthreads();
#pragma unroll
    for (int i = 0; i < 4; ++i) {
        int r = tr + i * 8;
        dst[(size_t)(n0 + r) * K + k0 + tc] = f2bf(tile[tc][r]);
    }
}

// ---------------- bf16 MFMA GEMM: C = act(A @ Bt^T + bias (+res)) ----------------
// A: [M,K] bf16 row-major. Bt: [N,K] bf16 (i.e. W^T). out: fp32 or bf16 [M,N].
// ACT: 0 none, 1 gelu. NBIAS: 1 single bias, 3 qkv-concat selector.
template<int ACT, int OUT_BF, int HAS_RES, int NBIAS>
__global__ __launch_bounds__(256) void gemm_k(
    const unsigned short* __restrict__ A,
    const unsigned short* __restrict__ Bt,
    const float* __restrict__ b0,
    const float* __restrict__ b1,
    const float* __restrict__ b2,
    const float* __restrict__ res,
    void* __restrict__ out,
    int M, int N, int K)
{
    __shared__ __align__(16) unsigned short As[64][40];
    __shared__ __align__(16) unsigned short Bs[64][40];
    const int t = threadIdx.x;
    const int m0 = blockIdx.x * 64;
    const int n0 = blockIdx.y * 64;
    const int lane = t & 63;
    const int wave = t >> 6;
    const int wm = wave >> 1;
    const int wn = wave & 1;
    const int l15 = lane & 15;
    const int kr = (lane >> 4) * 8;

    v4f acc[2][2] = {};

    const int ar = t >> 2;
    const int ac = (t & 3) * 8;
    const size_t arowA = (size_t)(m0 + ar) * K + ac;
    const size_t arowB = (size_t)(n0 + ar) * K + ac;

    for (int k0 = 0; k0 < K; k0 += 32) {
        __syncthreads();
        *(uint4*)(&As[ar][ac]) = *(const uint4*)(&A[arowA + k0]);
        *(uint4*)(&Bs[ar][ac]) = *(const uint4*)(&Bt[arowB + k0]);
        __syncthreads();
        v8s av0 = *(const v8s*)(&As[wm * 32 + 0 + l15][kr]);
        v8s av1 = *(const v8s*)(&As[wm * 32 + 16 + l15][kr]);
        v8s bv0 = *(const v8s*)(&Bs[wn * 32 + 0 + l15][kr]);
        v8s bv1 = *(const v8s*)(&Bs[wn * 32 + 16 + l15][kr]);
        acc[0][0] = __builtin_amdgcn_mfma_f32_16x16x32_bf16(av0, bv0, acc[0][0], 0, 0, 0);
        acc[0][1] = __builtin_amdgcn_mfma_f32_16x16x32_bf16(av0, bv1, acc[0][1], 0, 0, 0);
        acc[1][0] = __builtin_amdgcn_mfma_f32_16x16x32_bf16(av1, bv0, acc[1][0], 0, 0, 0);
        acc[1][1] = __builtin_amdgcn_mfma_f32_16x16x32_bf16(av1, bv1, acc[1][1], 0, 0, 0);
    }

    const int rb = (lane >> 4) * 4;
#pragma unroll
    for (int fm = 0; fm < 2; ++fm)
#pragma unroll
        for (int fn = 0; fn < 2; ++fn)
#pragma unroll
            for (int i = 0; i < 4; ++i) {
                int row = m0 + wm * 32 + fm * 16 + rb + i;
                int col = n0 + wn * 32 + fn * 16 + l15;
                float v = acc[fm][fn][i];
                float bb;
                if (NBIAS == 3) {
                    int which = (col >= 1536) ? 2 : (col >= 768 ? 1 : 0);
                    const float* bp = (which == 0) ? b0 : ((which == 1) ? b1 : b2);
                    bb = bp[col - which * 768];
                } else {
                    bb = b0[col];
                }
                v += bb;
                if (HAS_RES) v += res[(size_t)row * N + col];
                if (ACT == 1) v = 0.5f * v * (1.0f + erff(v * 0.70710678118654752f));
                size_t oi = (size_t)row * N + col;
                if (OUT_BF) ((unsigned short*)out)[oi] = f2bf(v);
                else        ((float*)out)[oi] = v;
            }
}

// ---------------- LayerNorm (row = 768), writes fp32 + bf16 ----------------
__global__ __launch_bounds__(256) void ln_k(
    const float* __restrict__ in, const float* __restrict__ g, const float* __restrict__ be,
    float* __restrict__ outf, unsigned short* __restrict__ outb)
{
    const int row = blockIdx.x;
    const float* x = in + (size_t)row * H_;
    const int t = threadIdx.x;
    const int wave = t >> 6, lane = t & 63;
    float v0 = x[t], v1 = x[t + 256], v2 = x[t + 512];
    float s = v0 + v1 + v2;
    float s2 = v0 * v0 + v1 * v1 + v2 * v2;
#pragma unroll
    for (int o = 32; o; o >>= 1) { s += __shfl_xor(s, o); s2 += __shfl_xor(s2, o); }
    __shared__ float rs[4], rq[4];
    if (lane == 0) { rs[wave] = s; rq[wave] = s2; }
    __syncthreads();
    s  = rs[0] + rs[1] + rs[2] + rs[3];
    s2 = rq[0] + rq[1] + rq[2] + rq[3];
    const float mean = s * (1.0f / 768.0f);
    float var = s2 * (1.0f / 768.0f) - mean * mean;
    var = fmaxf(var, 0.0f);
    const float inv = rsqrtf(var + 1e-12f);
#pragma unroll
    for (int i = 0; i < 3; ++i) {
        int c = t + i * 256;
        float vv = (i == 0) ? v0 : ((i == 1) ? v1 : v2);
        float y = (vv - mean) * inv * g[c] + be[c];
        outf[(size_t)row * H_ + c] = y;
        outb[(size_t)row * H_ + c] = f2bf(y);
    }
}

// ---------------- Attention (fp32, scores in LDS, TQ=8 rows/block) ----------------
__global__ __launch_bounds__(256) void attn_k(
    const float* __restrict__ qkv, const int* __restrict__ mask, float* __restrict__ ctx)
{
    const int qt = blockIdx.x;   // S/8 = 128
    const int h  = blockIdx.y;   // NH
    const int b  = blockIdx.z;   // B
    const int q0 = qt * 8;
    const int t = threadIdx.x;
    const int wave = t >> 6, lane = t & 63;

    __shared__ __align__(16) float qs[8][64];
    __shared__ __align__(16) float ss[8][1024];
    __shared__ float red[4][64];

    const size_t rstr = 2304;
    const float* qbase = qkv + (size_t)b * S_ * rstr + h * 64;
    for (int i = t; i < 512; i += 256) {
        int r = i >> 6, d = i & 63;
        qs[r][d] = qbase[(size_t)(q0 + r) * rstr + d];
    }
    __syncthreads();

    // scores: thread t owns cols {t, t+256, t+512, t+768}
    float p[4][8];
#pragma unroll
    for (int jj = 0; jj < 4; ++jj)
#pragma unroll
        for (int r = 0; r < 8; ++r) p[jj][r] = 0.0f;

    const float* kbase = qkv + (size_t)b * S_ * rstr + 768 + h * 64;
#pragma unroll 4
    for (int d4 = 0; d4 < 16; ++d4) {
        float4 qv[8];
#pragma unroll
        for (int r = 0; r < 8; ++r) qv[r] = *(const float4*)&qs[r][d4 * 4];
#pragma unroll
        for (int jj = 0; jj < 4; ++jj) {
            const int j = t + jj * 256;
            float4 kv = *(const float4*)&kbase[(size_t)j * rstr + d4 * 4];
#pragma unroll
            for (int r = 0; r < 8; ++r)
                p[jj][r] += qv[r].x * kv.x + qv[r].y * kv.y + qv[r].z * kv.z + qv[r].w * kv.w;
        }
    }
    const float scale = 0.125f;
#pragma unroll
    for (int jj = 0; jj < 4; ++jj) {
        const int j = t + jj * 256;
#pragma unroll
        for (int r = 0; r < 8; ++r) {
            int mval = mask[((size_t)b * S_ + q0 + r) * S_ + j];
            ss[r][j] = p[jj][r] * scale + (mval ? 0.0f : -10000.0f);
        }
    }
    __syncthreads();

    // softmax: wave w handles rows w and w+4
#pragma unroll
    for (int rr = 0; rr < 2; ++rr) {
        const int r = wave + rr * 4;
        float loc[16];
        float mx = -3.0e38f;
#pragma unroll
        for (int i = 0; i < 16; ++i) { loc[i] = ss[r][lane + 64 * i]; mx = fmaxf(mx, loc[i]); }
#pragma unroll
        for (int o = 32; o; o >>= 1) mx = fmaxf(mx, __shfl_xor(mx, o));
        float sum = 0.0f;
#pragma unroll
        for (int i = 0; i < 16; ++i) { float e = __expf(loc[i] - mx); loc[i] = e; sum += e; }
#pragma unroll
        for (int o = 32; o; o >>= 1) sum += __shfl_xor(sum, o);
        const float inv = 1.0f / sum;
#pragma unroll
        for (int i = 0; i < 16; ++i) ss[r][lane + 64 * i] = loc[i] * inv;
    }
    __syncthreads();

    // ctx: group g covers j in [g*256, g*256+256); lane d owns output dim d
    {
        const int g = wave, d = lane;
        const float* vbase = qkv + (size_t)b * S_ * rstr + 1536 + h * 64 + d;
        float acc[8];
#pragma unroll
        for (int r = 0; r < 8; ++r) acc[r] = 0.0f;
        for (int j = g * 256; j < (g + 1) * 256; ++j) {
            float vv = vbase[(size_t)j * rstr];
#pragma unroll
            for (int r = 0; r < 8; ++r) acc[r] += ss[r][j] * vv;
        }
#pragma unroll
        for (int r = 0; r < 8; ++r) {
            red[g][d] = acc[r];
            __syncthreads();
            if (g == 0) {
                float o4 = red[0][d] + red[1][d] + red[2][d] + red[3][d];
                ctx[((size_t)b * S_ + q0 + r) * H_ + h * 64 + d] = o4;
            }
            __syncthreads();
        }
    }
}

extern "C" void kernel_launch(void* const* d_in, const int* in_sizes, int n_in,
                              void* d_out, int out_size, void* d_ws, size_t ws_size,
                              hipStream_t stream)
{
    const float* x   = (const float*)d_in[0];
    const int*   mask= (const int*)  d_in[1];
    const float* Wq  = (const float*)d_in[2];
    const float* bq  = (const float*)d_in[3];
    const float* Wk  = (const float*)d_in[4];
    const float* bk  = (const float*)d_in[5];
    const float* Wv  = (const float*)d_in[6];
    const float* bv  = (const float*)d_in[7];
    const float* Wao = (const float*)d_in[8];
    const float* bao = (const float*)d_in[9];
    const float* g1  = (const float*)d_in[10];
    const float* b1  = (const float*)d_in[11];
    const float* Wi  = (const float*)d_in[12];
    const float* bi  = (const float*)d_in[13];
    const float* Wfo = (const float*)d_in[14];
    const float* bfo = (const float*)d_in[15];
    const float* g2  = (const float*)d_in[16];
    const float* b2  = (const float*)d_in[17];
    float* out = (float*)d_out;

    const int M = B_ * S_; // 2048
    char* base = (char*)d_ws;
    size_t off = 0;
    auto alloc = [&](size_t bytes) -> char* {
        char* p = base + off;
        off = (off + bytes + 255) & ~(size_t)255;
        return p;
    };

    unsigned short* WqkvT = (unsigned short*)alloc((size_t)L_ * 2304 * 768 * 2);
    unsigned short* WaoT  = (unsigned short*)alloc((size_t)L_ * 768 * 768 * 2);
    unsigned short* WiT   = (unsigned short*)alloc((size_t)L_ * 3072 * 768 * 2);
    unsigned short* WfoT  = (unsigned short*)alloc((size_t)L_ * 768 * 3072 * 2);
    unsigned short* h_bf  = (unsigned short*)alloc((size_t)M * 768 * 2);
    float* qkv            = (float*)alloc((size_t)M * 2304 * 4);
    float* ctx            = (float*)alloc((size_t)M * 768 * 4);
    unsigned short* ctxbf = (unsigned short*)alloc((size_t)M * 768 * 2);
    float* t1             = (float*)alloc((size_t)M * 768 * 4);
    float* attnf          = (float*)alloc((size_t)M * 768 * 4);
    unsigned short* attnbf= (unsigned short*)alloc((size_t)M * 768 * 2);
    float* hcur           = (float*)alloc((size_t)M * 768 * 4);
    // inter (bf16, 2048x3072) aliases qkv (dead after attention; 12.6MB <= 18.9MB)
    unsigned short* interbf = (unsigned short*)(void*)qkv;

    dim3 tb(256);
    // Weight transposes for all layers (z = layer)
    transpose_convert<<<dim3(24, 24, L_), tb, 0, stream>>>(Wq,  WqkvT + 0,          768,  768, (size_t)768 * 768,  (size_t)2304 * 768);
    transpose_convert<<<dim3(24, 24, L_), tb, 0, stream>>>(Wk,  WqkvT + 768 * 768,  768,  768, (size_t)768 * 768,  (size_t)2304 * 768);
    transpose_convert<<<dim3(24, 24, L_), tb, 0, stream>>>(Wv,  WqkvT + 1536 * 768, 768,  768, (size_t)768 * 768,  (size_t)2304 * 768);
    transpose_convert<<<dim3(24, 24, L_), tb, 0, stream>>>(Wao, WaoT,               768,  768, (size_t)768 * 768,  (size_t)768 * 768);
    transpose_convert<<<dim3(24, 96, L_), tb, 0, stream>>>(Wi,  WiT,                768, 3072, (size_t)768 * 3072, (size_t)3072 * 768);
    transpose_convert<<<dim3(96, 24, L_), tb, 0, stream>>>(Wfo, WfoT,              3072,  768, (size_t)3072 * 768, (size_t)768 * 3072);

    conv_bf16_k<<<(M * 768 + 255) / 256, 256, 0, stream>>>(x, h_bf, M * 768);

    const float* hres = x;
    for (int l = 0; l < L_; ++l) {
        // QKV projection (fused, N=2304)
        gemm_k<0, 0, 0, 3><<<dim3(32, 36), tb, 0, stream>>>(
            h_bf, WqkvT + (size_t)l * 2304 * 768,
            bq + l * 768, bk + l * 768, bv + l * 768, nullptr, qkv, M, 2304, 768);
        // Attention
        attn_k<<<dim3(128, NH_, B_), tb, 0, stream>>>(qkv, mask, ctx);
        conv_bf16_k<<<(M * 768 + 255) / 256, 256, 0, stream>>>(ctx, ctxbf, M * 768);
        // Attention output projection + residual
        gemm_k<0, 0, 1, 1><<<dim3(32, 12), tb, 0, stream>>>(
            ctxbf, WaoT + (size_t)l * 768 * 768,
            bao + l * 768, nullptr, nullptr, hres, t1, M, 768, 768);
        ln_k<<<M, tb, 0, stream>>>(t1, g1 + l * 768, b1 + l * 768, attnf, attnbf);
        // FFN1 + GELU (bf16 out)
        gemm_k<1, 1, 0, 1><<<dim3(32, 48), tb, 0, stream>>>(
            attnbf, WiT + (size_t)l * 3072 * 768,
            bi + l * 3072, nullptr, nullptr, nullptr, interbf, M, 3072, 768);
        // FFN2 + residual
        gemm_k<0, 0, 1, 1><<<dim3(32, 12), tb, 0, stream>>>(
            interbf, WfoT + (size_t)l * 3072 * 768,
            bfo + l * 768, nullptr, nullptr, attnf, t1, M, 768, 3072);
        float* of = (l == L_ - 1) ? out : hcur;
        ln_k<<<M, tb, 0, stream>>>(t1, g2 + l * 768, b2 + l * 768, of, h_bf);
        hres = hcur;
    }
}

// Round 3
// 815.710 us; speedup vs baseline: 2.1602x; 2.1602x over previous
//
#include <hip/hip_runtime.h>
#include <math.h>

// Problem dims
#define B_  2
#define S_  1024
#define H_  768
#define NH_ 12
#define DH_ 64
#define FF_ 3072
#define L_  4

typedef short v8s __attribute__((ext_vector_type(8)));
typedef float v4f __attribute__((ext_vector_type(4)));

static __device__ __forceinline__ unsigned short f2bf(float f) {
    unsigned int u = __float_as_uint(f);
    unsigned int r = (u + 0x7fffu + ((u >> 16) & 1u)) >> 16;
    return (unsigned short)r;
}

// ---------------- fp32 -> bf16 convert ----------------
__global__ void conv_bf16_k(const float* __restrict__ in, unsigned short* __restrict__ out, int n) {
    int i = blockIdx.x * 256 + threadIdx.x;
    if (i < n) out[i] = f2bf(in[i]);
}

// ---------------- fp32 [K,N] -> bf16 [N,K] transpose-convert ----------------
__global__ __launch_bounds__(256) void transpose_convert(
    const float* __restrict__ W, unsigned short* __restrict__ Wt,
    int K, int N, size_t in_lstride, size_t out_lstride)
{
    __shared__ float tile[32][33];
    const int l = blockIdx.z;
    const float* src = W + (size_t)l * in_lstride;
    unsigned short* dst = Wt + (size_t)l * out_lstride;
    const int k0 = blockIdx.x * 32;
    const int n0 = blockIdx.y * 32;
    const int t = threadIdx.x;
    const int tc = t & 31, tr = t >> 5;
#pragma unroll
    for (int i = 0; i < 4; ++i) {
        int r = tr + i * 8;
        tile[r][tc] = src[(size_t)(k0 + r) * N + n0 + tc];
    }
    __syncthreads();
#pragma unroll
    for (int i = 0; i < 4; ++i) {
        int r = tr + i * 8;
        dst[(size_t)(n0 + r) * K + k0 + tc] = f2bf(tile[tc][r]);
    }
}

// ---------------- bf16 MFMA GEMM: C = act(A @ Bt^T + bias (+res)) ----------------
template<int ACT, int OUT_BF, int HAS_RES, int NBIAS>
__global__ __launch_bounds__(256) void gemm_k(
    const unsigned short* __restrict__ A,
    const unsigned short* __restrict__ Bt,
    const float* __restrict__ b0,
    const float* __restrict__ b1,
    const float* __restrict__ b2,
    const float* __restrict__ res,
    void* __restrict__ out,
    int M, int N, int K)
{
    __shared__ __align__(16) unsigned short As[64][40];
    __shared__ __align__(16) unsigned short Bs[64][40];
    const int t = threadIdx.x;
    const int m0 = blockIdx.x * 64;
    const int n0 = blockIdx.y * 64;
    const int lane = t & 63;
    const int wave = t >> 6;
    const int wm = wave >> 1;
    const int wn = wave & 1;
    const int l15 = lane & 15;
    const int kr = (lane >> 4) * 8;

    v4f acc[2][2] = {};

    const int ar = t >> 2;
    const int ac = (t & 3) * 8;
    const size_t arowA = (size_t)(m0 + ar) * K + ac;
    const size_t arowB = (size_t)(n0 + ar) * K + ac;

    for (int k0 = 0; k0 < K; k0 += 32) {
        __syncthreads();
        *(uint4*)(&As[ar][ac]) = *(const uint4*)(&A[arowA + k0]);
        *(uint4*)(&Bs[ar][ac]) = *(const uint4*)(&Bt[arowB + k0]);
        __syncthreads();
        v8s av0 = *(const v8s*)(&As[wm * 32 + 0 + l15][kr]);
        v8s av1 = *(const v8s*)(&As[wm * 32 + 16 + l15][kr]);
        v8s bv0 = *(const v8s*)(&Bs[wn * 32 + 0 + l15][kr]);
        v8s bv1 = *(const v8s*)(&Bs[wn * 32 + 16 + l15][kr]);
        acc[0][0] = __builtin_amdgcn_mfma_f32_16x16x32_bf16(av0, bv0, acc[0][0], 0, 0, 0);
        acc[0][1] = __builtin_amdgcn_mfma_f32_16x16x32_bf16(av0, bv1, acc[0][1], 0, 0, 0);
        acc[1][0] = __builtin_amdgcn_mfma_f32_16x16x32_bf16(av1, bv0, acc[1][0], 0, 0, 0);
        acc[1][1] = __builtin_amdgcn_mfma_f32_16x16x32_bf16(av1, bv1, acc[1][1], 0, 0, 0);
    }

    const int rb = (lane >> 4) * 4;
#pragma unroll
    for (int fm = 0; fm < 2; ++fm)
#pragma unroll
        for (int fn = 0; fn < 2; ++fn)
#pragma unroll
            for (int i = 0; i < 4; ++i) {
                int row = m0 + wm * 32 + fm * 16 + rb + i;
                int col = n0 + wn * 32 + fn * 16 + l15;
                float v = acc[fm][fn][i];
                float bb;
                if (NBIAS == 3) {
                    int which = (col >= 1536) ? 2 : (col >= 768 ? 1 : 0);
                    const float* bp = (which == 0) ? b0 : ((which == 1) ? b1 : b2);
                    bb = bp[col - which * 768];
                } else {
                    bb = b0[col];
                }
                v += bb;
                if (HAS_RES) v += res[(size_t)row * N + col];
                if (ACT == 1) v = 0.5f * v * (1.0f + erff(v * 0.70710678118654752f));
                size_t oi = (size_t)row * N + col;
                if (OUT_BF) ((unsigned short*)out)[oi] = f2bf(v);
                else        ((float*)out)[oi] = v;
            }
}

// ---------------- LayerNorm (row = 768), writes fp32 + bf16 ----------------
__global__ __launch_bounds__(256) void ln_k(
    const float* __restrict__ in, const float* __restrict__ g, const float* __restrict__ be,
    float* __restrict__ outf, unsigned short* __restrict__ outb)
{
    const int row = blockIdx.x;
    const float* x = in + (size_t)row * H_;
    const int t = threadIdx.x;
    const int wave = t >> 6, lane = t & 63;
    float v0 = x[t], v1 = x[t + 256], v2 = x[t + 512];
    float s = v0 + v1 + v2;
    float s2 = v0 * v0 + v1 * v1 + v2 * v2;
#pragma unroll
    for (int o = 32; o; o >>= 1) { s += __shfl_xor(s, o); s2 += __shfl_xor(s2, o); }
    __shared__ float rs[4], rq[4];
    if (lane == 0) { rs[wave] = s; rq[wave] = s2; }
    __syncthreads();
    s  = rs[0] + rs[1] + rs[2] + rs[3];
    s2 = rq[0] + rq[1] + rq[2] + rq[3];
    const float mean = s * (1.0f / 768.0f);
    float var = s2 * (1.0f / 768.0f) - mean * mean;
    var = fmaxf(var, 0.0f);
    const float inv = rsqrtf(var + 1e-12f);
#pragma unroll
    for (int i = 0; i < 3; ++i) {
        int c = t + i * 256;
        float vv = (i == 0) ? v0 : ((i == 1) ? v1 : v2);
        float y = (vv - mean) * inv * g[c] + be[c];
        outf[(size_t)row * H_ + c] = y;
        outb[(size_t)row * H_ + c] = f2bf(y);
    }
}

// ---------------- Flash attention, bf16 MFMA ----------------
// Grid: (S/64, NH, B). Block 256 = 4 waves, each wave owns 16 q-rows.
// qkv: [B*S][2304] bf16 (q|k|v). ctx out: [B*S][768] bf16.
__global__ __launch_bounds__(256) void fattn_k(
    const unsigned short* __restrict__ qkv,
    const int* __restrict__ mask,
    unsigned short* __restrict__ ctx)
{
    const int qt = blockIdx.x, h = blockIdx.y, b = blockIdx.z;
    const int q0 = qt * 64;
    const int t = threadIdx.x;
    const int wave = t >> 6, lane = t & 63;
    const int l15 = lane & 15;
    const int kr8 = (lane >> 4) * 8;
    const int rb  = (lane >> 4) * 4;
    const int wq0 = wave * 16;

    // K tile [64 keys][64 d], padded rows (144B) -> 2-way reads
    __shared__ __align__(16) unsigned short Ks[64][72];
    // P tile [64 q][64 k], padded
    __shared__ __align__(16) unsigned short Ps[64][72];
    // V^T tile, linear [d][key] with XOR swizzle (128B rows can't be padded
    // without breaking 16B alignment; swizzle byte ^= ((d&7)^(d>>3))<<4 gives
    // <=2-way conflicts on both packed-u32 transpose writes and b128 reads)
    __shared__ __align__(16) unsigned short VtL[64 * 64];

    const size_t rstr = 2304;
    const unsigned short* base = qkv + (size_t)b * S_ * rstr + h * 64;

    // Q fragments (wave's 16 rows), held in regs for the whole block
    v8s qf0, qf1;
    {
        const unsigned short* qp = base + (size_t)(q0 + wq0 + l15) * rstr + kr8;
        qf0 = *(const v8s*)qp;
        qf1 = *(const v8s*)(qp + 32);
    }

    // staging assignment
    const int skp = t >> 3;       // 0..31
    const int sch = t & 7;        // 0..7
    const int sd0 = sch * 8;

    float m_[4], l_[4];
    v4f accO[4];
#pragma unroll
    for (int i = 0; i < 4; ++i) { m_[i] = -3.0e38f; l_[i] = 0.f; }
#pragma unroll
    for (int f = 0; f < 4; ++f) accO[f] = (v4f){0.f, 0.f, 0.f, 0.f};

    const int* mrow[4];
#pragma unroll
    for (int i = 0; i < 4; ++i)
        mrow[i] = mask + ((size_t)(b * S_) + q0 + wq0 + rb + i) * S_;

    for (int kt = 0; kt < 16; ++kt) {
        const int k0 = kt * 64;
        __syncthreads();
        // ---- stage K (straight) and V (transposed+swizzled) ----
        {
            const unsigned short* kp = base + 768 + (size_t)(k0 + skp) * rstr + sd0;
            v8s kv0 = *(const v8s*)kp;
            v8s kv1 = *(const v8s*)(kp + 32 * rstr);
            *(v8s*)&Ks[skp][sd0] = kv0;
            *(v8s*)&Ks[skp + 32][sd0] = kv1;
            const unsigned short* vp = base + 1536 + (size_t)(k0 + 2 * skp) * rstr + sd0;
            v8s va = *(const v8s*)vp;
            v8s vb = *(const v8s*)(vp + rstr);
#pragma unroll
            for (int j = 0; j < 8; ++j) {
                const int d = sd0 + j;
                const int sw = ((d & 7) ^ (d >> 3)) << 3;   // element-unit swizzle
                unsigned int pk = ((unsigned int)(unsigned short)vb[j] << 16) | (unsigned short)va[j];
                *(unsigned int*)&VtL[(size_t)d * 64 + ((2 * skp) ^ sw)] = pk;
            }
        }
        __syncthreads();

        // ---- QK^T: D[q=rb+i][key=f*16+l15] ----
        v4f s4[4];
#pragma unroll
        for (int f = 0; f < 4; ++f) s4[f] = (v4f){0.f, 0.f, 0.f, 0.f};
#pragma unroll
        for (int ks = 0; ks < 2; ++ks) {
            v8s qv = ks ? qf1 : qf0;
#pragma unroll
            for (int f = 0; f < 4; ++f) {
                v8s kf = *(const v8s*)&Ks[f * 16 + l15][ks * 32 + kr8];
                s4[f] = __builtin_amdgcn_mfma_f32_16x16x32_bf16(qv, kf, s4[f], 0, 0, 0);
            }
        }

        // ---- mask + scale + online softmax ----
        float p[4][4];
        float mx[4];
#pragma unroll
        for (int i = 0; i < 4; ++i) mx[i] = -3.0e38f;
#pragma unroll
        for (int f = 0; f < 4; ++f)
#pragma unroll
            for (int i = 0; i < 4; ++i) {
                int mval = mrow[i][k0 + f * 16 + l15];
                float v = s4[f][i] * 0.125f + (mval ? 0.f : -10000.f);
                p[f][i] = v;
                mx[i] = fmaxf(mx[i], v);
            }
#pragma unroll
        for (int o = 8; o; o >>= 1)
#pragma unroll
            for (int i = 0; i < 4; ++i) mx[i] = fmaxf(mx[i], __shfl_xor(mx[i], o));
        float corr[4], rsum[4];
#pragma unroll
        for (int i = 0; i < 4; ++i) {
            float mn = fmaxf(m_[i], mx[i]);
            corr[i] = __expf(m_[i] - mn);
            m_[i] = mn;
            rsum[i] = 0.f;
        }
#pragma unroll
        for (int f = 0; f < 4; ++f)
#pragma unroll
            for (int i = 0; i < 4; ++i) {
                float e = __expf(p[f][i] - m_[i]);
                p[f][i] = e;
                rsum[i] += e;
            }
#pragma unroll
        for (int o = 8; o; o >>= 1)
#pragma unroll
            for (int i = 0; i < 4; ++i) rsum[i] += __shfl_xor(rsum[i], o);
#pragma unroll
        for (int i = 0; i < 4; ++i) l_[i] = l_[i] * corr[i] + rsum[i];
#pragma unroll
        for (int f = 0; f < 4; ++f)
#pragma unroll
            for (int i = 0; i < 4; ++i) accO[f][i] *= corr[i];

        // ---- P -> LDS (wave-private rows; in-wave LDS ordering suffices) ----
#pragma unroll
        for (int f = 0; f < 4; ++f)
#pragma unroll
            for (int i = 0; i < 4; ++i)
                Ps[wq0 + rb + i][f * 16 + l15] = f2bf(p[f][i]);

        // ---- PV: accO[q][d] += P[q][k] V[k][d] ----
#pragma unroll
        for (int ks = 0; ks < 2; ++ks) {
            v8s pf = *(const v8s*)&Ps[wq0 + l15][ks * 32 + kr8];
#pragma unroll
            for (int f = 0; f < 4; ++f) {
                const int d = f * 16 + l15;
                const int sw = ((d & 7) ^ (d >> 3)) << 3;
                v8s vf = *(const v8s*)&VtL[(size_t)d * 64 + ((ks * 32 + kr8) ^ sw)];
                accO[f] = __builtin_amdgcn_mfma_f32_16x16x32_bf16(pf, vf, accO[f], 0, 0, 0);
            }
        }
    }

    // ---- epilogue: O = accO / l ----
#pragma unroll
    for (int f = 0; f < 4; ++f)
#pragma unroll
        for (int i = 0; i < 4; ++i) {
            float o = accO[f][i] / l_[i];
            size_t row = (size_t)(b * S_) + q0 + wq0 + rb + i;
            ctx[row * 768 + h * 64 + f * 16 + l15] = f2bf(o);
        }
}

extern "C" void kernel_launch(void* const* d_in, const int* in_sizes, int n_in,
                              void* d_out, int out_size, void* d_ws, size_t ws_size,
                              hipStream_t stream)
{
    const float* x   = (const float*)d_in[0];
    const int*   mask= (const int*)  d_in[1];
    const float* Wq  = (const float*)d_in[2];
    const float* bq  = (const float*)d_in[3];
    const float* Wk  = (const float*)d_in[4];
    const float* bk  = (const float*)d_in[5];
    const float* Wv  = (const float*)d_in[6];
    const float* bv  = (const float*)d_in[7];
    const float* Wao = (const float*)d_in[8];
    const float* bao = (const float*)d_in[9];
    const float* g1  = (const float*)d_in[10];
    const float* b1  = (const float*)d_in[11];
    const float* Wi  = (const float*)d_in[12];
    const float* bi  = (const float*)d_in[13];
    const float* Wfo = (const float*)d_in[14];
    const float* bfo = (const float*)d_in[15];
    const float* g2  = (const float*)d_in[16];
    const float* b2  = (const float*)d_in[17];
    float* out = (float*)d_out;

    const int M = B_ * S_; // 2048
    char* base = (char*)d_ws;
    size_t off = 0;
    auto alloc = [&](size_t bytes) -> char* {
        char* p = base + off;
        off = (off + bytes + 255) & ~(size_t)255;
        return p;
    };

    unsigned short* WqkvT = (unsigned short*)alloc((size_t)L_ * 2304 * 768 * 2);
    unsigned short* WaoT  = (unsigned short*)alloc((size_t)L_ * 768 * 768 * 2);
    unsigned short* WiT   = (unsigned short*)alloc((size_t)L_ * 3072 * 768 * 2);
    unsigned short* WfoT  = (unsigned short*)alloc((size_t)L_ * 768 * 3072 * 2);
    unsigned short* h_bf  = (unsigned short*)alloc((size_t)M * 768 * 2);
    unsigned short* qkvbf = (unsigned short*)alloc((size_t)M * 2304 * 2);
    unsigned short* ctxbf = (unsigned short*)alloc((size_t)M * 768 * 2);
    float* t1             = (float*)alloc((size_t)M * 768 * 4);
    float* attnf          = (float*)alloc((size_t)M * 768 * 4);
    unsigned short* attnbf= (unsigned short*)alloc((size_t)M * 768 * 2);
    float* hcur           = (float*)alloc((size_t)M * 768 * 4);
    unsigned short* interbf = (unsigned short*)alloc((size_t)M * FF_ * 2);

    dim3 tb(256);
    transpose_convert<<<dim3(24, 24, L_), tb, 0, stream>>>(Wq,  WqkvT + 0,          768,  768, (size_t)768 * 768,  (size_t)2304 * 768);
    transpose_convert<<<dim3(24, 24, L_), tb, 0, stream>>>(Wk,  WqkvT + 768 * 768,  768,  768, (size_t)768 * 768,  (size_t)2304 * 768);
    transpose_convert<<<dim3(24, 24, L_), tb, 0, stream>>>(Wv,  WqkvT + 1536 * 768, 768,  768, (size_t)768 * 768,  (size_t)2304 * 768);
    transpose_convert<<<dim3(24, 24, L_), tb, 0, stream>>>(Wao, WaoT,               768,  768, (size_t)768 * 768,  (size_t)768 * 768);
    transpose_convert<<<dim3(24, 96, L_), tb, 0, stream>>>(Wi,  WiT,                768, 3072, (size_t)768 * 3072, (size_t)3072 * 768);
    transpose_convert<<<dim3(96, 24, L_), tb, 0, stream>>>(Wfo, WfoT,              3072,  768, (size_t)3072 * 768, (size_t)768 * 3072);

    conv_bf16_k<<<(M * 768 + 255) / 256, 256, 0, stream>>>(x, h_bf, M * 768);

    const float* hres = x;
    for (int l = 0; l < L_; ++l) {
        // QKV projection (fused, N=2304, bf16 out)
        gemm_k<0, 1, 0, 3><<<dim3(32, 36), tb, 0, stream>>>(
            h_bf, WqkvT + (size_t)l * 2304 * 768,
            bq + l * 768, bk + l * 768, bv + l * 768, nullptr, qkvbf, M, 2304, 768);
        // Flash attention (bf16 MFMA)
        fattn_k<<<dim3(S_ / 64, NH_, B_), tb, 0, stream>>>(qkvbf, mask, ctxbf);
        // Attention output projection + residual
        gemm_k<0, 0, 1, 1><<<dim3(32, 12), tb, 0, stream>>>(
            ctxbf, WaoT + (size_t)l * 768 * 768,
            bao + l * 768, nullptr, nullptr, hres, t1, M, 768, 768);
        ln_k<<<M, tb, 0, stream>>>(t1, g1 + l * 768, b1 + l * 768, attnf, attnbf);
        // FFN1 + GELU (bf16 out)
        gemm_k<1, 1, 0, 1><<<dim3(32, 48), tb, 0, stream>>>(
            attnbf, WiT + (size_t)l * 3072 * 768,
            bi + l * 3072, nullptr, nullptr, nullptr, interbf, M, 3072, 768);
        // FFN2 + residual
        gemm_k<0, 0, 1, 1><<<dim3(32, 12), tb, 0, stream>>>(
            interbf, WfoT + (size_t)l * 3072 * 768,
            bfo + l * 768, nullptr, nullptr, attnf, t1, M, 768, 3072);
        float* of = (l == L_ - 1) ? out : hcur;
        ln_k<<<M, tb, 0, stream>>>(t1, g2 + l * 768, b2 + l * 768, of, h_bf);
        hres = hcur;
    }
}